// Round 4
// baseline (180.651 us; speedup 1.0000x reference)
//
#include <hip/hip_runtime.h>
#include <math.h>

#define NN 6144
#define DD 512
#define CAP 128

typedef __bf16 bf16_t;
typedef __bf16 bf16x8 __attribute__((ext_vector_type(8)));
typedef unsigned short u16x8 __attribute__((ext_vector_type(8)));
typedef float f32x4 __attribute__((ext_vector_type(4)));

__device__ __forceinline__ float bf2f(unsigned short u) {
    unsigned v = ((unsigned)u) << 16;
    return __builtin_bit_cast(float, v);
}
__device__ __forceinline__ unsigned short f2bf(float f) {
    unsigned u = __builtin_bit_cast(unsigned, f);
    u += 0x7fffu + ((u >> 16) & 1u);   // round-to-nearest-even
    return (unsigned short)(u >> 16);
}
__device__ __forceinline__ float sigmoidf_(float z) { return 1.0f / (1.0f + expf(-z)); }

// ================= kernel P: W transpose->bf16  +  gate projections =================
__global__ __launch_bounds__(256) void k_prep(const float* __restrict__ Wsa,
                                              const float* __restrict__ Wg,
                                              const float* __restrict__ x,
                                              const float* __restrict__ Wa,
                                              const float* __restrict__ Wb,
                                              unsigned short* __restrict__ wt,
                                              float* __restrict__ xal, float* __restrict__ xar,
                                              float* __restrict__ xbl, float* __restrict__ xbr) {
    __shared__ float s[64][65];
    int bid = blockIdx.x;
    if (bid < 128) {
        int n0 = (bid & 15) * 64;
        int k0 = (bid >> 4) * 64;
        int tx = threadIdx.x & 63, ty = threadIdx.x >> 6;
        const float* src = (n0 < 512) ? Wsa : Wg;
        int nn0 = n0 & 511;
#pragma unroll
        for (int kk = 0; kk < 64; kk += 4)
            s[kk + ty][tx] = src[(size_t)(k0 + kk + ty) * 512 + nn0 + tx];
        __syncthreads();
#pragma unroll
        for (int nn = 0; nn < 64; nn += 4)
            wt[(size_t)(n0 + nn + ty) * 512 + k0 + tx] = f2bf(s[tx][nn + ty]);
    } else {
        int wave = threadIdx.x >> 6, lane = threadIdx.x & 63;
        int row = (bid - 128) * 4 + wave;
        int k0 = lane * 8;
        const float* xr_ = x + (size_t)row * DD + k0;
        float4 v0 = *(const float4*)xr_;
        float4 v1 = *(const float4*)(xr_ + 4);
        float xv[8] = {v0.x, v0.y, v0.z, v0.w, v1.x, v1.y, v1.z, v1.w};
        float a0 = 0, a1 = 0, b0 = 0, b1 = 0;
#pragma unroll
        for (int j = 0; j < 8; j++) {
            a0 += xv[j] * Wa[k0 + j];
            a1 += xv[j] * Wa[512 + k0 + j];
            b0 += xv[j] * Wb[k0 + j];
            b1 += xv[j] * Wb[512 + k0 + j];
        }
#pragma unroll
        for (int off = 32; off; off >>= 1) {
            a0 += __shfl_down(a0, off); a1 += __shfl_down(a1, off);
            b0 += __shfl_down(b0, off); b1 += __shfl_down(b1, off);
        }
        if (lane == 0) { xal[row] = a0; xar[row] = a1; xbl[row] = b0; xbr[row] = b1; }
    }
}

// ===== kernel FUSED: {half-row-per-wave scan, atomic slot reservation} + {MFMA GEMM} =====
// 7680 blocks of 256. bid%5<4 -> scan block (4 waves x half-row each); bid%5==4 -> GEMM tile.
__global__ __launch_bounds__(256) void k_fused(const float* __restrict__ x,
                                               const bf16_t* __restrict__ wt,
                                               const float* __restrict__ adjA,
                                               const float* __restrict__ adjB,
                                               int* __restrict__ idxA, int* __restrict__ idxB,
                                               int* __restrict__ cntA, int* __restrict__ cntB,
                                               unsigned short* __restrict__ h,
                                               unsigned short* __restrict__ g) {
    int bid = blockIdx.x;
    int wave = threadIdx.x >> 6, lane = threadIdx.x & 63;
    int grp = bid % 5;
    if (grp < 4) {
        // ---------- scan: one wave = half an adjacency row; 12 uint4 loads; no LDS ----------
        int sid = (bid / 5) * 4 + grp;            // scan block id 0..6143
        int gw = sid * 4 + wave;                  // 0..24575
        int row = gw >> 1;                        // 0..12287
        int half = gw & 1;
        int which = row >= NN;
        int r = which ? row - NN : row;
        const float* adj = which ? adjB : adjA;
        int* idx = (which ? idxB : idxA) + (size_t)r * CAP;
        int* cnt = which ? cntB : cntA;

        const uint4* arow = (const uint4*)(adj + (size_t)r * NN) + half * 768 + lane;
        unsigned long long m = 0;
#pragma unroll
        for (int j = 0; j < 12; j++) {
            uint4 v = arow[j * 64];
            unsigned long long bits =
                (unsigned long long)(v.x != 0u) |
                ((unsigned long long)(v.y != 0u) << 1) |
                ((unsigned long long)(v.z != 0u) << 2) |
                ((unsigned long long)(v.w != 0u) << 3);
            m |= bits << (j * 4);
        }
        int c = (int)__popcll(m);
        int p = c;
#pragma unroll
        for (int off = 1; off < 64; off <<= 1) {
            int t = __shfl_up(p, off);
            if (lane >= off) p += t;
        }
        int total = __shfl(p, 63);
        int base = 0;
        if (lane == 0) base = atomicAdd(&cnt[r], total);
        base = __shfl(base, 0);
        int pos = base + p - c;
        while (m) {
            int b = __ffsll((long long)m) - 1;
            m &= m - 1;
            int col = ((half * 768) + ((b >> 2) * 64) + lane) * 4 + (b & 3);
            if (pos < CAP) idx[pos] = col;
            pos++;
        }
    } else {
        // ---------- GEMM tile: 64 rows x 64 cols, MFMA 16x16x32, A cvt in-register ----------
        int tt = bid / 5;                         // 0..1535
        int row0 = (tt % (NN / 64)) * 64 + wave * 16;
        int col0 = (tt / (NN / 64)) * 64;
        int lr = lane & 15;
        int kg = (lane >> 4) * 8;

        f32x4 acc[4] = {{0,0,0,0},{0,0,0,0},{0,0,0,0},{0,0,0,0}};
        const float* ap = x + (size_t)(row0 + lr) * DD + kg;
        const bf16_t* bp = wt + (size_t)(col0 + lr) * DD + kg;

        for (int k0 = 0; k0 < DD; k0 += 32) {
            float4 a0 = *(const float4*)(ap + k0);
            float4 a1 = *(const float4*)(ap + k0 + 4);
            u16x8 au;
            au[0] = f2bf(a0.x); au[1] = f2bf(a0.y); au[2] = f2bf(a0.z); au[3] = f2bf(a0.w);
            au[4] = f2bf(a1.x); au[5] = f2bf(a1.y); au[6] = f2bf(a1.z); au[7] = f2bf(a1.w);
            bf16x8 a = __builtin_bit_cast(bf16x8, au);
#pragma unroll
            for (int n = 0; n < 4; n++) {
                bf16x8 b = *(const bf16x8*)(bp + (size_t)n * 16 * DD + k0);
                acc[n] = __builtin_amdgcn_mfma_f32_16x16x32_bf16(a, b, acc[n], 0, 0, 0);
            }
        }
        int dcol = lane & 15;
        int dr0 = (lane >> 4) * 4;
#pragma unroll
        for (int n = 0; n < 4; n++) {
            int col = col0 + n * 16 + dcol;
            unsigned short* dst = (col < 512) ? h : g;
            int cc = col & 511;
#pragma unroll
            for (int rr = 0; rr < 4; rr++) {
                int mr = row0 + dr0 + rr;
                dst[(size_t)mr * 512 + cc] = f2bf(acc[n][rr]);
            }
        }
    }
}

// ================= kernel SLR: s_left / s_right (one row per wave) =================
__global__ __launch_bounds__(256) void k_slr(const unsigned short* __restrict__ h,
                                             const float* __restrict__ a_sa,
                                             float* __restrict__ sl, float* __restrict__ sr) {
    int wave = threadIdx.x >> 6, lane = threadIdx.x & 63;
    int row = blockIdx.x * 4 + wave;
    int k0 = lane * 8;
    uint4 hv = *(const uint4*)(h + (size_t)row * DD + k0);
    unsigned u[4] = {hv.x, hv.y, hv.z, hv.w};
    float s0 = 0, s1 = 0;
#pragma unroll
    for (int j = 0; j < 4; j++) {
        float h0 = bf2f((unsigned short)(u[j] & 0xffff));
        float h1 = bf2f((unsigned short)(u[j] >> 16));
        s0 += h0 * a_sa[k0 + 2 * j] + h1 * a_sa[k0 + 2 * j + 1];
        s1 += h0 * a_sa[512 + k0 + 2 * j] + h1 * a_sa[512 + k0 + 2 * j + 1];
    }
#pragma unroll
    for (int off = 32; off; off >>= 1) { s0 += __shfl_down(s0, off); s1 += __shfl_down(s1, off); }
    if (lane == 0) { sl[row] = s0; sr[row] = s1; }
}

// ================= kernel F: gates + attention normalize + gathers + epilogue =================
__global__ __launch_bounds__(256) void k_final(
    const int* __restrict__ idxA, const int* __restrict__ cntA,
    const int* __restrict__ idxB, const int* __restrict__ cntB,
    const unsigned short* __restrict__ h, const unsigned short* __restrict__ g,
    const float* __restrict__ sl, const float* __restrict__ sr,
    const float* __restrict__ xal, const float* __restrict__ xar,
    const float* __restrict__ xbl, const float* __restrict__ xbr,
    const float* __restrict__ ba, const float* __restrict__ bb,
    const float* __restrict__ bias, float* __restrict__ out) {
    int i = blockIdx.x;
    int tid = threadIdx.x;
    __shared__ float w[CAP];
    __shared__ int ja[CAP], jb[CAP];
    __shared__ float s_denom, s_ga, s_gb;

    int cA = cntA[i]; cA = cA > CAP ? CAP : cA;
    int cB = cntB[i]; cB = cB > CAP ? CAP : cB;
    if (tid < cA) {
        int j = idxA[(size_t)i * CAP + tid];
        ja[tid] = j;
        float s = sl[i] + sr[j];
        float lrelu = s > 0.f ? s : 0.01f * s;
        w[tid] = expf(-lrelu);
    }
    if (tid < cB) jb[tid] = idxB[(size_t)i * CAP + tid];
    __syncthreads();

    if (tid < 64) {
        float p = 0.f, gasum = 0.f, gbsum = 0.f;
        for (int t = tid; t < cA; t += 64) { p += w[t]; gasum += xal[ja[t]]; }
        for (int t = tid; t < cB; t += 64) gbsum += xbl[jb[t]];
#pragma unroll
        for (int off = 32; off; off >>= 1) {
            p += __shfl_down(p, off);
            gasum += __shfl_down(gasum, off);
            gbsum += __shfl_down(gbsum, off);
        }
        if (tid == 0) {
            s_denom = p;
            s_ga = sigmoidf_(gasum + xar[i] + ba[0]);
            s_gb = sigmoidf_(gbsum + xbr[i] + bb[0]);
        }
    }
    __syncthreads();
    float inv = 1.f / (s_denom + 1e-5f);
    float ga = s_ga, gb = s_gb;

    int d0 = tid * 2;
    float a0 = 0, a1 = 0, b0 = 0, b1 = 0;
#pragma unroll 4
    for (int t = 0; t < cA; t++) {
        unsigned hv = *(const unsigned*)(h + (size_t)ja[t] * 512 + d0);
        float wt_ = w[t];
        a0 += wt_ * bf2f((unsigned short)(hv & 0xffff));
        a1 += wt_ * bf2f((unsigned short)(hv >> 16));
    }
#pragma unroll 4
    for (int t = 0; t < cB; t++) {
        unsigned gv = *(const unsigned*)(g + (size_t)jb[t] * 512 + d0);
        b0 += bf2f((unsigned short)(gv & 0xffff));
        b1 += bf2f((unsigned short)(gv >> 16));
    }
    float z0 = ga * (a0 * inv) + gb * (b0 + bias[d0]);
    float z1 = ga * (a1 * inv) + gb * (b1 + bias[d0 + 1]);
    out[(size_t)i * 512 + d0]     = sigmoidf_(z0);
    out[(size_t)i * 512 + d0 + 1] = sigmoidf_(z1);
}

extern "C" void kernel_launch(void* const* d_in, const int* in_sizes, int n_in,
                              void* d_out, int out_size, void* d_ws, size_t ws_size,
                              hipStream_t stream) {
    const float* x    = (const float*)d_in[0];
    const float* adjA = (const float*)d_in[1];
    const float* adjB = (const float*)d_in[2];
    const float* Wsa  = (const float*)d_in[3];
    const float* a_sa = (const float*)d_in[4];
    const float* Wg   = (const float*)d_in[5];
    const float* bg   = (const float*)d_in[6];
    const float* Wa   = (const float*)d_in[7];
    const float* ba   = (const float*)d_in[8];
    const float* Wb   = (const float*)d_in[9];
    const float* bb   = (const float*)d_in[10];
    float* out = (float*)d_out;

    char* ws = (char*)d_ws;
    size_t off = 0;
    auto alloc = [&](size_t bytes) -> void* {
        void* p = ws + off;
        off += (bytes + 255) & ~(size_t)255;
        return p;
    };
    unsigned short* wt = (unsigned short*)alloc((size_t)1024 * DD * 2);
    unsigned short* h  = (unsigned short*)alloc((size_t)NN * DD * 2);
    unsigned short* g  = (unsigned short*)alloc((size_t)NN * DD * 2);
    int* idxA = (int*)alloc((size_t)NN * CAP * 4);
    int* idxB = (int*)alloc((size_t)NN * CAP * 4);
    int* cntA = (int*)alloc((size_t)NN * 4 * 2);   // cntA and cntB contiguous
    int* cntB = cntA + NN;
    float* xal = (float*)alloc((size_t)NN * 4);
    float* xar = (float*)alloc((size_t)NN * 4);
    float* xbl = (float*)alloc((size_t)NN * 4);
    float* xbr = (float*)alloc((size_t)NN * 4);
    float* sl = (float*)alloc((size_t)NN * 4);
    float* sr = (float*)alloc((size_t)NN * 4);

    // zero the atomic reservation counters (graph-capture-safe async memset)
    hipMemsetAsync(cntA, 0, (size_t)NN * 4 * 2, stream);
    // P: W transpose + gate projections
    k_prep<<<128 + NN / 4, 256, 0, stream>>>(Wsa, Wg, x, Wa, Wb, wt, xal, xar, xbl, xbr);
    // FUSED: half-row-per-wave scan (atomic slot reservation) interleaved with MFMA GEMM
    k_fused<<<7680, 256, 0, stream>>>(x, (const bf16_t*)wt, adjA, adjB,
                                      idxA, idxB, cntA, cntB, h, g);
    // SLR: s_left / s_right
    k_slr<<<NN / 4, 256, 0, stream>>>(h, a_sa, sl, sr);
    // F: gates + attention + GCN gather + sigmoid epilogue
    k_final<<<NN, 256, 0, stream>>>(idxA, cntA, idxB, cntB, h, g, sl, sr,
                                    xal, xar, xbl, xbr, ba, bb, bg, out);
}